// Round 16
// baseline (130.757 us; speedup 1.0000x reference)
//
#include <hip/hip_runtime.h>
#include <math.h>

#define NB 4
#define NC 128
#define NH 128
#define NW 128
#define NHW (NH*NW)
#define NCOUT 128

// ws float offsets
#define SY_OFF 0
#define SX_OFF 1179648
#define MK_OFF 2359296
#define WOFF_OFF 3538944    // 36 slabs [64][36] bf16 (offset-conv W)
#define WMAIN_OFF 3580416   // 36 slabs [128][36] bf16 (main W)
#define XT_OFF 3663360      // bf16 xT[b][cg16][y][x][8ch] : 8388608 shorts

typedef short short8 __attribute__((ext_vector_type(8)));
typedef float f32x4 __attribute__((ext_vector_type(4)));
typedef float f32x2 __attribute__((ext_vector_type(2)));

__device__ inline short f2bf(float f) {
    unsigned u = __float_as_uint(f);
    u = (u + 0x7FFFu + ((u >> 16) & 1u)) >> 16;   // RNE
    return (short)u;
}
__device__ inline unsigned pack2(float lo, float hi) {
    unsigned r;
    asm("v_cvt_pk_bf16_f32 %0, %1, %2" : "=v"(r) : "v"(lo), "v"(hi));
    return r;
}
__device__ inline unsigned pkf16(float a, float b) {
    auto h = __builtin_amdgcn_cvt_pkrtz(a, b);
    unsigned r; __builtin_memcpy(&r, &h, 4); return r;
}
__device__ inline float f16f(unsigned s) {
    unsigned short us = (unsigned short)s;
    __fp16 h; __builtin_memcpy(&h, &us, 2); return (float)h;
}
__device__ inline f32x2 pkmul(f32x2 a, f32x2 b) {
    f32x2 d; asm("v_pk_mul_f32 %0, %1, %2" : "=v"(d) : "v"(a), "v"(b)); return d;
}
__device__ inline f32x2 pkfma(f32x2 a, f32x2 b, f32x2 c) {
    f32x2 d; asm("v_pk_fma_f32 %0, %1, %2, %3" : "=v"(d) : "v"(a), "v"(b), "v"(c)); return d;
}
// corner uint (2 bf16) -> {lo_ch, hi_ch}; hi is RAW (mantissa noise <= 1 bf16 ulp)
__device__ inline f32x2 cpair(unsigned u) {
    f32x2 c; c.x = __uint_as_float(u << 16); c.y = __uint_as_float(u); return c;
}
__device__ inline void gload_lds16(const void* g, void* l) {
    __builtin_amdgcn_global_load_lds(
        (const __attribute__((address_space(1))) unsigned int*)g,
        (__attribute__((address_space(3))) unsigned int*)l, 16, 0, 0);
}

// ---------------------------------------------------------------------------
// wtrans: offset table 36 slabs [64][36] + main table 36 slabs [128][36] padded
// ---------------------------------------------------------------------------
__global__ void wtrans_kernel(const float* __restrict__ w_off,
                              const float* __restrict__ weight,
                              float* __restrict__ ws)
{
    int i = blockIdx.x * 256 + threadIdx.x;
    if (i < 36*2304) {
        int s = i / 2304, rem = i - s*2304;
        int row = rem / 36, c = rem - row*36;
        int chunk = s / 9, k2 = s - 9*chunk;
        float v = (row < 54 && c < 32) ? w_off[(row*NC + chunk*32 + c)*9 + k2] : 0.f;
        ((short*)(ws + WOFF_OFF))[i] = f2bf(v);
    } else if (i < 36*2304 + 36*4608) {
        int j = i - 36*2304;
        int s = j / 4608, rem = j - s*4608;
        int row = rem / 36, c = rem - row*36;
        int chunk = s / 9, k2 = s - 9*chunk;
        float v = (c < 32) ? weight[(row*NC + chunk*32 + c)*9 + k2] : 0.f;
        ((short*)(ws + WMAIN_OFF))[j] = f2bf(v);
    }
}

// ---------------------------------------------------------------------------
// xtrans: x NCHW fp32 -> xT[b][cg][y][x][8ch] bf16. Pure BW.
// ---------------------------------------------------------------------------
__global__ __launch_bounds__(256) void xtrans_kernel(
    const float* __restrict__ x, float* __restrict__ ws)
{
    short* xT = (short*)(ws + XT_OFF);
    const int bid = blockIdx.x;
    const int ys = bid & 15, cg = (bid >> 4) & 15, b = bid >> 8;
    const int col = threadIdx.x & 127, rr = threadIdx.x >> 7;
    const float* xb = x + ((long)(b*NC + cg*8))*NHW;
#pragma unroll
    for (int yy = 0; yy < 4; ++yy) {
        const int y = ys*8 + yy*2 + rr;
        const float* p = xb + y*NW + col;
        float v[8];
#pragma unroll
        for (int q = 0; q < 8; ++q) v[q] = p[q*NHW];
        uint4 u = make_uint4(pack2(v[0],v[1]), pack2(v[2],v[3]),
                             pack2(v[4],v[5]), pack2(v[6],v[7]));
        *(uint4*)&xT[(((long)(b*16+cg)*NH + y)*NW + col)*8] = u;
    }
}

// ---------------------------------------------------------------------------
// offconv: 3x3 conv (54 ch pad 64) as pure GEMM over xT. (R8-exact structure)
// ---------------------------------------------------------------------------
__global__ __launch_bounds__(512, 4) void offconv_kernel(
    float* __restrict__ ws, const float* __restrict__ b_off)
{
    __shared__ short wslab[2][2304];
    int bid = blockIdx.x;
    bid = (bid & 7) * 64 + (bid >> 3);      // XCD swizzle
    const int b   = bid >> 7;
    const int ho  = bid & 127;
    const int tid = threadIdx.x;
    const int lane = tid & 63;
    const int wid = tid >> 6;
    const int n = lane & 15, g = lane >> 4;
    const int px = wid*16 + n;
    const short* woff = (const short*)(ws + WOFF_OFF);
    const char*  xTb  = (const char*)((const short*)(ws + XT_OFF) + (long)b*16*NHW*8);

    f32x4 acc[4];
#pragma unroll
    for (int rf = 0; rf < 4; ++rf) acc[rf] = (f32x4){0.f,0.f,0.f,0.f};

    auto DMA = [&](int it, int buf) {
        if (tid < 288) gload_lds16(woff + it*2304 + tid*8, &wslab[buf][tid*8]);
    };
    auto LOADB = [&](int it) -> short8 {
        const int chunk = it/9, k2 = it - 9*chunk;
        const int y = ho + k2/3 - 1, xc = px + (k2%3) - 1;
        short8 bf = (short8){0,0,0,0,0,0,0,0};
        if ((unsigned)y < NH && (unsigned)xc < NW)
            bf = *(const short8*)(xTb + ((long)(chunk*4 + g)*NHW + y*NW + xc)*16);
        return bf;
    };

    DMA(0, 0);
    short8 bcur = LOADB(0);
    __syncthreads();

#pragma unroll 1
    for (int it = 0; it < 36; ++it) {
        const int cur = it & 1, nxt = cur ^ 1;
        short8 bnext;
        if (it < 35) { DMA(it+1, nxt); bnext = LOADB(it+1); }
        __builtin_amdgcn_sched_barrier(0);
#pragma unroll
        for (int rf = 0; rf < 4; ++rf) {
            short8 af = *(const short8*)&wslab[cur][(rf*16 + n)*36 + 8*g];
            acc[rf] = __builtin_amdgcn_mfma_f32_16x16x32_bf16(af, bcur, acc[rf], 0,0,0);
        }
        __syncthreads();
        bcur = bnext;
    }

#pragma unroll
    for (int rf = 0; rf < 4; ++rf) {
#pragma unroll
        for (int r = 0; r < 4; ++r) {
            int cout = 16*rf + 4*g + r;
            if (cout >= 54) continue;
            float v = acc[rf][r] + b_off[cout];
            if (cout < 36) {
                int og = cout / 18, rem = cout - 18*og;
                int k2c = rem >> 1, d = cout & 1;
                float base = d ? (float)(px - 1 + (k2c % 3))
                              : (float)(ho - 1 + (k2c / 3));
                ws[(d ? SX_OFF : SY_OFF) + (((b*2+og)*9 + k2c)*NHW) + ho*NW + px] = v + base;
            } else {
                int cc = cout - 36;
                int og = cc / 9, k2c = cc - 9*og;
                ws[MK_OFF + (((b*2+og)*9 + k2c)*NHW) + ho*NW + px] = 1.f/(1.f+expf(-v));
            }
        }
    }
}

// ---------------------------------------------------------------------------
// deform: block = (b, ho): 128 px x 128 cout, 512 threads = 8 waves.
// Swapped MFMA (A = sampled data in registers). GATHERS FROM LDS:
// per cin-chunk, stage rows ho-3..ho+4 x px -2..129 x 32ch (67.6KB) via
// global_load_lds; corner reads become ds_read_b128 (no TA/L1 line cost).
// Out-of-window samples (|off|>~2, rare) flagged at param build -> global
// fallback path (execz-skipped when absent). x-edge cells zero-padded
// (their weights are already 0). 1 block/CU (109KB LDS).
// ---------------------------------------------------------------------------
__global__ __launch_bounds__(512, 2) void deform_kernel(
    float* __restrict__ ws, const float* __restrict__ bias,
    float* __restrict__ out)
{
    __shared__ short4   pI[9][128];       //  9216 B global elem offsets (fallback)
    __shared__ unsigned pL[9][128];       //  4608 B packed local idx pair + flag
    __shared__ uint2    pWp[9][128];      //  9216 B 4 x f16 weights
    __shared__ short    xc[33792];        // 67584 B [slot8][lpx132][pl4][8ch]
    __shared__ short    wslab[2][4608];   // 18432 B

    int bid = blockIdx.x;
    bid = (bid & 7) * 64 + (bid >> 3);      // XCD swizzle (512 = 8*64)
    const int b   = bid >> 7;
    const int ho  = bid & 127;
    const int tid = threadIdx.x;
    const int lane = tid & 63;
    const int wid = tid >> 6;               // 0..7
    const int n = lane & 15, g = lane >> 4;
    const int pxl = 16*wid + n;             // thread's pixel 0..127
    const short* wmn = (const short*)(ws + WMAIN_OFF);
    const char*  xTb = (const char*)((const short*)(ws + XT_OFF) + (long)b*16*NHW*8);

    f32x4 acc[8];
#pragma unroll
    for (int rf = 0; rf < 8; ++rf) acc[rf] = (f32x4){0.f,0.f,0.f,0.f};

    auto DMA = [&](int slabIdx, int buf) {
        const short* src = wmn + slabIdx*4608;
        gload_lds16(src + tid*8, &wslab[buf][tid*8]);
        if (tid < 64) gload_lds16(src + 4096 + tid*8, &wslab[buf][4096 + tid*8]);
    };
    // stage 8 rows x 128 valid px x 4 planes (4096 x 16B); slot wave-uniform
    auto XSTAGE = [&](int chunk) {
#pragma unroll 1
        for (int u = tid; u < 4096; u += 512) {
            const int slot = u >> 9, rem = u & 511;
            const int gx = rem >> 2, pl = rem & 3;
            const int gy = min(max(ho - 3 + slot, 0), NH-1);
            const short* src = (const short*)xTb +
                ((long)(chunk*4 + pl)*NHW + gy*NW + gx)*8;
            gload_lds16(src, &xc[((slot*132 + gx + 2)*4 + pl)*8]);
        }
    };

    // zero-fill x-edge cells (lpx 0,1,130,131), once (constant forever)
    for (int u = tid; u < 128; u += 512) {
        const int slot = u >> 4, e = (u >> 2) & 3, pl = u & 3;
        const int lpx = (e < 2) ? e : (128 + e);
        *(uint4*)&xc[((slot*132 + lpx)*4 + pl)*8] = make_uint4(0,0,0,0);
    }

    // LDS corner gather (fast path) + rare global fallback
#define GLOADL(k2, chunk, G0, G1, G2, G3) do {                          \
        const unsigned pv_ = pL[(k2)][pxl];                             \
        const unsigned i0_ = pv_ & 0xFFFFu;                             \
        const unsigned i1_ = (pv_ >> 16) & 0x7FFFu;                     \
        const short* b0_ = &xc[(i0_*4 + g)*8];                          \
        const short* b1_ = &xc[(i1_*4 + g)*8];                          \
        G0 = *(const uint4*)b0_;                                        \
        G1 = *(const uint4*)(b0_ + 32);   /* x+1 px: +4 units = 64B */  \
        G2 = *(const uint4*)b1_;                                        \
        G3 = *(const uint4*)(b1_ + 32);                                 \
        if (__builtin_expect((pv_ >> 31) != 0, 0)) {                    \
            const short4 I_ = pI[(k2)][pxl];                            \
            const char* xp_ = xTb + (long)((chunk)*4 + g)*(NHW*16);     \
            G0 = *(const uint4*)(xp_ + (((int)I_.x) << 4));             \
            G1 = *(const uint4*)(xp_ + (((int)I_.y) << 4));             \
            G2 = *(const uint4*)(xp_ + (((int)I_.z) << 4));             \
            G3 = *(const uint4*)(xp_ + (((int)I_.w) << 4));             \
        }                                                               \
    } while (0)

#define FIN(k2, G0, G1, G2, G3, Adst) do {                              \
        const uint2 wp_ = *(const uint2*)&pWp[(k2)][pxl];               \
        const float w0s = f16f(wp_.x), w1s = f16f(wp_.x >> 16);         \
        const float w2s = f16f(wp_.y), w3s = f16f(wp_.y >> 16);         \
        const f32x2 W0_ = {w0s, w0s}, W1_ = {w1s, w1s};                 \
        const f32x2 W2_ = {w2s, w2s}, W3_ = {w3s, w3s};                 \
        uint4 u_; unsigned* up_ = (unsigned*)&u_;                       \
        const unsigned* a_ = (const unsigned*)&G0;                      \
        const unsigned* b_ = (const unsigned*)&G1;                      \
        const unsigned* c_ = (const unsigned*)&G2;                      \
        const unsigned* d_ = (const unsigned*)&G3;                      \
        _Pragma("unroll")                                               \
        for (int e = 0; e < 4; ++e) {                                   \
            f32x2 r_ = pkmul(cpair(d_[e]), W3_);                        \
            r_ = pkfma(cpair(c_[e]), W2_, r_);                          \
            r_ = pkfma(cpair(b_[e]), W1_, r_);                          \
            r_ = pkfma(cpair(a_[e]), W0_, r_);                          \
            up_[e] = pack2(r_.x, r_.y);                                 \
        }                                                               \
        __builtin_memcpy(&Adst, &u_, 16);                               \
    } while (0)

#define MFMA8(Ain, buf) do {                                            \
        _Pragma("unroll")                                               \
        for (int rf = 0; rf < 8; ++rf) {                                \
            short8 bf = *(const short8*)&wslab[(buf)][(16*rf + n)*36 + 8*g]; \
            acc[rf] = __builtin_amdgcn_mfma_f32_16x16x32_bf16(Ain, bf, acc[rf], 0,0,0); \
        }                                                               \
    } while (0)

    uint4 G0, G1, G2, G3;
    short8 A;

#pragma unroll 1
    for (int og = 0; og < 2; ++og) {
        __syncthreads();    // zero-fill done / prior og's reads done
        // ---- build bilinear params for this og (9 rows x 128 px)
        for (int e = tid; e < 1152; e += 512) {
            const int row = e >> 7, p = e & 127;
            const int sidx = (((b*2+og)*9 + row)*NHW) + ho*NW + p;
            const float sy = ws[SY_OFF + sidx];
            const float sx = ws[SX_OFF + sidx];
            const float m  = ws[MK_OFF + sidx];
            const float y0f = floorf(sy), x0f = floorf(sx);
            const float ly = sy - y0f, lx = sx - x0f;
            const int y0 = (int)y0f, x0i = (int)x0f;
            const int y1 = y0 + 1, x1 = x0i + 1;
            const bool vy0 = (unsigned)y0 < NH, vy1 = (unsigned)y1 < NH;
            const bool vx0 = (unsigned)x0i < NW, vx1 = (unsigned)x1 < NW;
            const int cy0 = min(max(y0,0),NH-1), cy1 = min(max(y1,0),NH-1);
            const int cx0 = min(max(x0i,0),NW-1), cx1 = min(max(x1,0),NW-1);
            pI[row][p] = make_short4(
                (short)(cy0*NW + cx0), (short)(cy0*NW + cx1),
                (short)(cy1*NW + cx0), (short)(cy1*NW + cx1));
            const int basex = min(max(x0i, -1), NW-1);
            int s0 = cy0 - ho + 3, s1 = cy1 - ho + 3;
            const unsigned flag =
                ((unsigned)s0 > 7u || (unsigned)s1 > 7u) ? (1u << 31) : 0u;
            s0 = min(max(s0, 0), 7); s1 = min(max(s1, 0), 7);
            const unsigned i0 = (unsigned)(s0*132 + basex + 2);
            const unsigned i1 = (unsigned)(s1*132 + basex + 2);
            pL[row][p] = i0 | (i1 << 16) | flag;
            const float W0 = (vy0 && vx0) ? (1.f-ly)*(1.f-lx)*m : 0.f;
            const float W1 = (vy0 && vx1) ? (1.f-ly)*lx*m       : 0.f;
            const float W2 = (vy1 && vx0) ? ly*(1.f-lx)*m       : 0.f;
            const float W3 = (vy1 && vx1) ? ly*lx*m             : 0.f;
            pWp[row][p] = make_uint2(pkf16(W0, W1), pkf16(W2, W3));
        }
        __syncthreads();

#pragma unroll 1
        for (int cc = 0; cc < 2; ++cc) {
            const int chunk = og*2 + cc;
            if (cc) __syncthreads();     // prior chunk's xc/wslab reads done
            XSTAGE(chunk);
            DMA(chunk*9, 0);
            asm volatile("s_waitcnt vmcnt(0) lgkmcnt(0)" ::: "memory");
            __builtin_amdgcn_s_barrier();
            __builtin_amdgcn_sched_barrier(0);

#pragma unroll 1
            for (int k2 = 0; k2 < 9; ++k2) {
                const int buf = k2 & 1;
                if (k2 < 8) DMA(chunk*9 + k2 + 1, buf ^ 1);
                GLOADL(k2, chunk, G0, G1, G2, G3);
                FIN(k2, G0, G1, G2, G3, A);
                MFMA8(A, buf);
                if (k2 < 8) {
                    asm volatile("s_waitcnt vmcnt(0) lgkmcnt(0)" ::: "memory");
                    __builtin_amdgcn_s_barrier();
                    __builtin_amdgcn_sched_barrier(0);
                }
            }
        }
    }
#undef GLOADL
#undef FIN
#undef MFMA8

    // ---- epilogue: D row = px (16wid+4g+r), col = cout (16rf+n)
#pragma unroll
    for (int rf = 0; rf < 8; ++rf) {
        const int cout = 16*rf + n;
        const float bb = bias[cout];
        float4 o = make_float4(acc[rf][0]+bb, acc[rf][1]+bb,
                               acc[rf][2]+bb, acc[rf][3]+bb);
        *(float4*)&out[((b*NCOUT + cout)*NH + ho)*NW + 16*wid + 4*g] = o;
    }
}

// ---------------------------------------------------------------------------
extern "C" void kernel_launch(void* const* d_in, const int* in_sizes, int n_in,
                              void* d_out, int out_size, void* d_ws, size_t ws_size,
                              hipStream_t stream)
{
    const float* x      = (const float*)d_in[0];
    const float* w_off  = (const float*)d_in[1];
    const float* b_off  = (const float*)d_in[2];
    const float* weight = (const float*)d_in[3];
    const float* bias   = (const float*)d_in[4];
    float* out = (float*)d_out;
    float* ws  = (float*)d_ws;

    hipLaunchKernelGGL(wtrans_kernel, dim3(972), dim3(256), 0, stream,
                       w_off, weight, ws);
    hipLaunchKernelGGL(xtrans_kernel, dim3(1024), dim3(256), 0, stream,
                       x, ws);
    hipLaunchKernelGGL(offconv_kernel, dim3(NB*NH), dim3(512), 0, stream,
                       ws, b_off);
    hipLaunchKernelGGL(deform_kernel, dim3(NB*NH), dim3(512), 0, stream,
                       ws, bias, out);
}